// Round 1
// 241.993 us; speedup vs baseline: 1.0275x; 1.0275x over previous
//
#include <hip/hip_runtime.h>

#define NN 10000
#define EE 100000
#define CC 32
#define GG 64
#define EPSV 1e-5f
#define NB 8               // src nodes per fused block
#define SLOTS 1056         // 32*32 P-slots + 32 bias slots (w2r layout [i][slot])
#define HST 32             // h row stride: 32 floats = 128B, fully coalesced (bias read from P2[32])
#define PST 36             // P2 c-stride per o-row (c=0..31 data, 32 bias, 33..35 pad)
#define PNODE (32*PST)     // 1152 floats per node in LDS
#define EBLK (EE/8)        // 12500 blocks in k_h (8 CSR slots each)
#define HBLK ((EE+255)/256)// 391 hist blocks in k_pre
#define WBLK 160           // w2t blocks in k_pre: 5 per i, i=0..31

// ---------------- k_pre: degree histograms + weight transposes (runs FIRST now) --------
__global__ __launch_bounds__(256) void k_pre(const int* __restrict__ ei,
        int* __restrict__ cnt, int* __restrict__ deg,
        const float* __restrict__ w2a, const float* __restrict__ b2a,
        const float* __restrict__ w2b, const float* __restrict__ b2b,
        float* __restrict__ w2r1, float* __restrict__ w2r2) {
    int blk = blockIdx.x;
    int t = threadIdx.x;
    if (blk < HBLK) {
        int e = blk * 256 + t;
        if (e < EE) {
            atomicAdd(&cnt[ei[EE + e]], 1);   // dst in-degree
            atomicAdd(&deg[ei[e]], 1);        // src out-degree
        }
    } else {
        int b2i = blk - HBLK;                 // 0..159
        int s = (b2i % 5) * 256 + t;
        int i = b2i / 5;
        if (s < SLOTS) {
            float va = (s < 1024) ? w2a[(s >> 5) * 1024 + i * 32 + (s & 31)]
                                  : b2a[i * 32 + (s - 1024)];
            float vb = (s < 1024) ? w2b[(s >> 5) * 1024 + i * 32 + (s & 31)]
                                  : b2b[i * 32 + (s - 1024)];
            w2r1[i * SLOTS + s] = va;
            w2r2[i * SLOTS + s] = vb;
        }
    }
}

// ---------------- exclusive scan of deg[NN] -> rowptr[NN+1] AND cursor copy ----------------
__global__ __launch_bounds__(1024) void k_scan(const int* __restrict__ deg,
                                               int* __restrict__ rowptr,
                                               int* __restrict__ cursor) {
    __shared__ int buf[1024];
    int t = threadIdx.x;
    int v[10]; int s = 0;
    int base = t * 10;
    #pragma unroll
    for (int k = 0; k < 10; k++) {
        int idx = base + k;
        v[k] = (idx < NN) ? deg[idx] : 0;
        s += v[k];
    }
    buf[t] = s;
    for (int off = 1; off < 1024; off <<= 1) {
        __syncthreads();
        int val = buf[t] + ((t >= off) ? buf[t - off] : 0);
        __syncthreads();
        buf[t] = val;
    }
    __syncthreads();
    int carry = (t > 0) ? buf[t - 1] : 0;
    #pragma unroll
    for (int k = 0; k < 10; k++) {
        int idx = base + k;
        if (idx < NN) { rowptr[idx] = carry; cursor[idx] = carry; }
        carry += v[k];
    }
    if (t == 1023) rowptr[NN] = buf[1023];
}

// ---------------- scatter: CSR slot assignment + packed (src,dst) meta ----------------
__global__ void k_scatter(const int* __restrict__ ei,
                          int* __restrict__ cursor, int* __restrict__ csr_eid,
                          int2* __restrict__ meta) {
    int e = blockIdx.x * blockDim.x + threadIdx.x;
    if (e >= EE) return;
    int s = ei[e];
    int d = ei[EE + e];
    int pos = atomicAdd(&cursor[s], 1);
    csr_eid[pos] = e;
    meta[pos] = make_int2(s, d);
}

// ---------------- k_h: per-edge h for BOTH layers, written in CSR-slot order ----------
// Reads edge_attr gathered via csr_eid (16B broadcast, L2-resident); writes are
// perfectly coalesced 128B rows at hbuf[pos*32].
__global__ __launch_bounds__(256) void k_h(const float* __restrict__ edge_attr,
        const float* __restrict__ w1a, const float* __restrict__ b1a,
        const float* __restrict__ w1b, const float* __restrict__ b1b,
        const int* __restrict__ csr_eid,
        float* __restrict__ hbuf1, float* __restrict__ hbuf2) {
    int t = threadIdx.x;
    int pos = blockIdx.x * 8 + (t >> 5);
    int o = t & 31;
    int e = csr_eid[pos];
    float4 a = *(const float4*)&edge_attr[(size_t)e * 4];
    float ha = fmaxf(a.x * w1a[o] + a.y * w1a[32 + o] + a.z * w1a[64 + o] + a.w * w1a[96 + o] + b1a[o], 0.f);
    float hb = fmaxf(a.x * w1b[o] + a.y * w1b[32 + o] + a.z * w1b[64 + o] + a.w * w1b[96 + o] + b1b[o], 0.f);
    hbuf1[(size_t)pos * HST + o] = ha;
    hbuf2[(size_t)pos * HST + o] = hb;
}

// ---------------- fused NNConv: P in LDS + edge pass (chain-free Phase B) -------------
// R8: all Phase-B load addresses are pure functions of loop index `pos`:
//   meta[pos] (int2 src,dst) + hbuf[pos*32] (8x float4). No csr_eid->ei->hbuf chase.
__global__ __launch_bounds__(256, 3) void k_fused3(const float* __restrict__ x,
        const float* __restrict__ hbuf,
        const float* __restrict__ w2r,
        const int2* __restrict__ meta, const int* __restrict__ rowptr,
        float* __restrict__ agg) {
    __shared__ float xs[NB][32];
    __shared__ float P2[NB * PNODE];     // 8*1152*4 = 36,864 B
    int t = threadIdx.x;
    int o = t & 31;
    int cb = 4 * (t >> 5);               // base c (0,4,...,28)
    int n0 = blockIdx.x * NB;

    xs[t >> 5][t & 31] = x[n0 * 32 + t];
    __syncthreads();

    // ---- Phase A: P2[n][o][c] = sum_i x[n,i] * w2r[i][c*32+o] ----
    {
        float acc[4][NB];
        #pragma unroll
        for (int k = 0; k < 4; k++)
            #pragma unroll
            for (int n = 0; n < NB; n++) acc[k][n] = 0.f;
        #pragma unroll
        for (int j = 0; j < 8; j++) {
            float wk[4][4];
            #pragma unroll
            for (int r = 0; r < 4; r++)
                #pragma unroll
                for (int k = 0; k < 4; k++)
                    wk[r][k] = w2r[(4 * j + r) * SLOTS + (cb + k) * 32 + o];
            #pragma unroll
            for (int n = 0; n < NB; n++) {
                float4 xq = *(const float4*)&xs[n][4 * j];
                #pragma unroll
                for (int k = 0; k < 4; k++)
                    acc[k][n] += xq.x * wk[0][k] + xq.y * wk[1][k]
                               + xq.z * wk[2][k] + xq.w * wk[3][k];
            }
        }
        #pragma unroll
        for (int n = 0; n < NB; n++) {
            float4 st = make_float4(acc[0][n], acc[1][n], acc[2][n], acc[3][n]);
            *(float4*)&P2[n * PNODE + o * PST + cb] = st;
        }
    }
    if (t < 32) {
        float wb[32];
        #pragma unroll
        for (int i = 0; i < 32; i++) wb[i] = w2r[i * SLOTS + 1024 + t];
        #pragma unroll
        for (int n = 0; n < NB; n++) {
            float b = 0.f;
            #pragma unroll
            for (int j = 0; j < 8; j++) {
                float4 xq = *(const float4*)&xs[n][4 * j];
                b += xq.x * wb[4 * j] + xq.y * wb[4 * j + 1]
                   + xq.z * wb[4 * j + 2] + xq.w * wb[4 * j + 3];
            }
            *(float4*)&P2[n * PNODE + t * PST + 32] = make_float4(b, 0.f, 0.f, 0.f);
        }
    }
    __syncthreads();

    // ---- Phase B: 32-lane group per edge; meta+h prefetched one edge ahead;
    //      all addresses derived from pos (no dependent-load chain) ----
    int ebase = rowptr[n0];
    int eend  = rowptr[n0 + NB];
    int grp = t >> 5;
    int pos = ebase + grp;
    int src_c = 0, dst_c = 0;
    float4 hq[8];
    if (pos < eend) {
        int2 sd = meta[pos];
        src_c = sd.x; dst_c = sd.y;
        const float* hb = &hbuf[(size_t)pos * HST];
        #pragma unroll
        for (int b = 0; b < 8; b++) hq[b] = *(const float4*)&hb[4 * b];
    }
    while (pos < eend) {
        int pos_n = pos + 8;
        int src_n = 0, dst_n = 0;
        float4 hq_n[8];
        if (pos_n < eend) {                     // prefetch next edge (independent loads)
            int2 sd = meta[pos_n];
            src_n = sd.x; dst_n = sd.y;
            const float* hbn = &hbuf[(size_t)pos_n * HST];
            #pragma unroll
            for (int b = 0; b < 8; b++) hq_n[b] = *(const float4*)&hbn[4 * b];
        }
        const float* Pn = &P2[(src_c - n0) * PNODE + o * PST];
        float msg = Pn[32];                     // bias slot (replaces old pad quad)
        #pragma unroll
        for (int b = 0; b < 8; b++) {
            float4 pq = *(const float4*)&Pn[4 * b];      // ds_read_b128
            msg += hq[b].x * pq.x + hq[b].y * pq.y
                 + hq[b].z * pq.z + hq[b].w * pq.w;
        }
        atomicAdd(&agg[(size_t)dst_c * 32 + o], msg);
        pos = pos_n; src_c = src_n; dst_c = dst_n;
        #pragma unroll
        for (int b = 0; b < 8; b++) hq[b] = hq_n[b];
    }
}

// ---------------- combine: agg/cnt + x@root + bias -> BN -> ReLU ----------------
__global__ __launch_bounds__(256) void k_combine(const float* __restrict__ x_in,
        float* __restrict__ agg, const int* __restrict__ cnt,
        const float* __restrict__ root, const float* __restrict__ bias,
        const float* __restrict__ bng, const float* __restrict__ bnb,
        const float* __restrict__ bnm, const float* __restrict__ bnv,
        float* __restrict__ x_out, float* __restrict__ psum,
        const int* __restrict__ batch) {
    __shared__ float xs[8][32];
    __shared__ float vals[8][32];
    __shared__ int gb[8];
    int t = threadIdx.x;
    int n0 = blockIdx.x * 8;
    xs[t >> 5][t & 31] = x_in[n0 * 32 + t];
    __syncthreads();
    int k = t >> 5, o = t & 31, n = n0 + k;
    float r = bias[o];
    #pragma unroll
    for (int i = 0; i < 32; i++) r += xs[k][i] * root[i * 32 + o];
    float a = agg[(size_t)n * 32 + o] / fmaxf((float)cnt[n], 1.f);
    float val = a + r;
    val = (val - bnm[o]) * rsqrtf(bnv[o] + EPSV) * bng[o] + bnb[o];
    val = fmaxf(val, 0.f);
    if (x_out) {
        x_out[(size_t)n * 32 + o] = val;
        agg[(size_t)n * 32 + o] = 0.f;        // re-zero for layer 2
    }
    if (psum) {
        vals[k][o] = val;
        if (o == 0) gb[k] = batch[n];
        __syncthreads();
        if (k == 0) {
            float acc = vals[0][o];
            int g = gb[0];
            #pragma unroll
            for (int k2 = 1; k2 < 8; k2++) {
                if (gb[k2] == g) acc += vals[k2][o];
                else {
                    atomicAdd(&psum[(size_t)g * 32 + o], acc);
                    g = gb[k2]; acc = vals[k2][o];
                }
            }
            atomicAdd(&psum[(size_t)g * 32 + o], acc);
        }
    }
}

// ---------------- global mean pool + readout MLP ----------------
__global__ __launch_bounds__(256) void k_readout(const float* __restrict__ psum,
        const int* __restrict__ batch,
        const float* __restrict__ r1w, const float* __restrict__ r1b,
        const float* __restrict__ r2w, const float* __restrict__ r2b,
        float* __restrict__ out) {
    __shared__ float w1s[32 * 16];
    __shared__ float b1s[16];
    __shared__ float w2s[16];
    __shared__ float ps[GG * 32];
    int t = threadIdx.x;
    int cnt_g = 0;
    if (t < GG) {
        int lo = 0, hi = NN;
        while (lo < hi) { int m = (lo + hi) >> 1; if (batch[m] < t) lo = m + 1; else hi = m; }
        int lb = lo;
        lo = 0; hi = NN;
        while (lo < hi) { int m = (lo + hi) >> 1; if (batch[m] < t + 1) lo = m + 1; else hi = m; }
        cnt_g = lo - lb;
    }
    w1s[t] = r1w[t];
    w1s[t + 256] = r1w[t + 256];
    if (t < 16) { b1s[t] = r1b[t]; w2s[t] = r2w[t]; }
    #pragma unroll
    for (int i = 0; i < GG * 32 / 256; i++) ps[t + i * 256] = psum[t + i * 256];
    __syncthreads();
    if (t < GG) {
        float inv = 1.f / fmaxf((float)cnt_g, 1.f);
        float acc = r2b[0];
        #pragma unroll
        for (int j = 0; j < 16; j++) {
            float dot = 0.f;
            #pragma unroll
            for (int c = 0; c < 32; c++) dot += ps[t * 32 + c] * w1s[c * 16 + j];
            float z = dot * inv + b1s[j];
            acc += fmaxf(z, 0.f) * w2s[j];
        }
        out[t] = acc;
    }
}

extern "C" void kernel_launch(void* const* d_in, const int* in_sizes, int n_in,
                              void* d_out, int out_size, void* d_ws, size_t ws_size,
                              hipStream_t stream) {
    const float* x       = (const float*)d_in[0];
    const float* eattr   = (const float*)d_in[1];
    const float* e1_w1   = (const float*)d_in[2];
    const float* e1_b1   = (const float*)d_in[3];
    const float* e1_w2   = (const float*)d_in[4];
    const float* e1_b2   = (const float*)d_in[5];
    const float* root1   = (const float*)d_in[6];
    const float* bias1   = (const float*)d_in[7];
    const float* e2_w1   = (const float*)d_in[8];
    const float* e2_b1   = (const float*)d_in[9];
    const float* e2_w2   = (const float*)d_in[10];
    const float* e2_b2   = (const float*)d_in[11];
    const float* root2   = (const float*)d_in[12];
    const float* bias2   = (const float*)d_in[13];
    const float* bn1_g   = (const float*)d_in[14];
    const float* bn1_b   = (const float*)d_in[15];
    const float* bn1_m   = (const float*)d_in[16];
    const float* bn1_v   = (const float*)d_in[17];
    const float* bn2_g   = (const float*)d_in[18];
    const float* bn2_b   = (const float*)d_in[19];
    const float* bn2_m   = (const float*)d_in[20];
    const float* bn2_v   = (const float*)d_in[21];
    const float* r1_w    = (const float*)d_in[22];
    const float* r1_b    = (const float*)d_in[23];
    const float* r2_w    = (const float*)d_in[24];
    const float* r2_b    = (const float*)d_in[25];
    const int*   ei      = (const int*)d_in[26];
    const int*   batch   = (const int*)d_in[27];

    // workspace layout (bytes) — zeroed buffers contiguous for a single memset
    char* ws = (char*)d_ws;
    float* hbuf1  = (float*)(ws);                   // 12,800,000
    float* hbuf2  = (float*)(ws + 12800000);        // 12,800,000
    float* w2r1   = (float*)(ws + 25600000);        // 135,168
    float* w2r2   = (float*)(ws + 25735168);        // 135,168
    // ---- zero region start (1,368,192 B) ----
    float* agg    = (float*)(ws + 25870336);        // 1,280,000
    int*   cnt    = (int*)  (ws + 27150336);        // 40,000
    int*   deg    = (int*)  (ws + 27190336);        // 40,000
    float* psum   = (float*)(ws + 27230336);        // 8,192
    // ---- zero region end ----
    float* xmid   = (float*)(ws + 27238528);        // 1,280,000
    int*   rowptr = (int*)  (ws + 28518528);        // 40,064
    int*   cursor = (int*)  (ws + 28558592);        // 40,000
    int*   csr    = (int*)  (ws + 28598592);        // 400,000
    int2*  meta   = (int2*) (ws + 28998592);        // 800,000
    // total ~29.8 MB

    hipMemsetAsync(ws + 25870336, 0, 1368192, stream);   // agg+cnt+deg+psum

    // degree hists + weight transposes (must precede scan/scatter)
    k_pre<<<HBLK + WBLK, 256, 0, stream>>>(ei, cnt, deg,
                                           e1_w2, e1_b2, e2_w2, e2_b2, w2r1, w2r2);
    k_scan<<<1, 1024, 0, stream>>>(deg, rowptr, cursor);
    k_scatter<<<(EE + 255) / 256, 256, 0, stream>>>(ei, cursor, csr, meta);
    // per-edge h (both layers) written directly in CSR-slot order
    k_h<<<EBLK, 256, 0, stream>>>(eattr, e1_w1, e1_b1, e2_w1, e2_b1, csr, hbuf1, hbuf2);

    // ---- layer 1 ----
    k_fused3<<<NN / NB, 256, 0, stream>>>(x, hbuf1, w2r1, meta, rowptr, agg);
    k_combine<<<NN / 8, 256, 0, stream>>>(x, agg, cnt, root1, bias1,
                                          bn1_g, bn1_b, bn1_m, bn1_v,
                                          xmid, nullptr, batch);

    // ---- layer 2 ----
    k_fused3<<<NN / NB, 256, 0, stream>>>(xmid, hbuf2, w2r2, meta, rowptr, agg);
    k_combine<<<NN / 8, 256, 0, stream>>>(xmid, agg, cnt, root2, bias2,
                                          bn2_g, bn2_b, bn2_m, bn2_v,
                                          nullptr, psum, batch);

    // ---- pool + readout ----
    k_readout<<<1, 256, 0, stream>>>(psum, batch, r1_w, r1_b, r2_w, r2_b, (float*)d_out);
}